// Round 8
// baseline (73.228 us; speedup 1.0000x reference)
//
#include <hip/hip_runtime.h>
#include <stdint.h>

typedef _Float16 half8 __attribute__((ext_vector_type(8)));
typedef __fp16 fp16x2 __attribute__((ext_vector_type(2)));
typedef float f32x4 __attribute__((ext_vector_type(4)));
typedef float f32x2 __attribute__((ext_vector_type(2)));
typedef uint32_t u32x2 __attribute__((ext_vector_type(2)));

#define N_ 32
#define C_ 8
#define W_ 65536
#define F_ 16
#define OW_ 65473
#define K_ 512
#define TILE_T 1024
#define XS 1152              // halfs per channel row in an x buffer (1024+halo)
#define XBUF (C_ * XS)       // 9216 halfs = 18 KB

// funnel16(hi, lo) = (hi:lo) >> 16  -> v_alignbit_b32
__device__ __forceinline__ uint32_t funnel16(uint32_t hi, uint32_t lo) {
  return (uint32_t)((((uint64_t)hi << 32) | (uint64_t)lo) >> 16);
}

// pack two f32 -> one dword of 2x f16 (v_cvt_pkrtz_f16_f32)
__device__ __forceinline__ uint32_t pk(float a, float b) {
  union { fp16x2 h; uint32_t u; } cv;
  cv.h = __builtin_amdgcn_cvt_pkrtz(a, b);
  return cv.u;
}

// w LDS swizzle (half-index, mult of 4): XOR chunk idx with bits 6-8
__device__ __forceinline__ uint32_t wswz(uint32_t e) {
  uint32_t ch = e >> 3;
  ch ^= (ch >> 6) & 7u;
  return (ch << 4) | ((e & 7u) << 1);
}

__device__ __forceinline__ f32x4 ldx(const float* p) {
  return *reinterpret_cast<const f32x4*>(p);
}

// ---- x staging: 2176 f32x4 units per tile = 8 ch x 272; half h covers
// channels 4h..4h+3 (units h*1088 .. h*1088+1087). ----
__device__ __forceinline__ f32x4 xunit_load(const float* __restrict__ xn,
                                            int t0, int u, bool guard) {
  int ch = u / 272;
  int pos = (u - ch * 272) * 4;    // 0..1084
  int gi = t0 + pos;
  if (guard && gi >= W_) return (f32x4){0.f, 0.f, 0.f, 0.f};
  return ldx(xn + (size_t)ch * W_ + gi);
}

__device__ __forceinline__ void xunit_write(_Float16* __restrict__ xb,
                                            int u, f32x4 v) {
  int ch = u / 272;
  int pos = (u - ch * 272) * 4;
  u32x2 p; p[0] = pk(v[0], v[1]); p[1] = pk(v[2], v[3]);
  *reinterpret_cast<u32x2*>(reinterpret_cast<char*>(xb) +
                            (size_t)(ch * XS + pos) * 2u) = p;
}

__device__ __forceinline__ void xload_half(const float* __restrict__ xn, int t0,
                                           int tid, bool guard, int h,
                                           f32x4 pre[3]) {
  const int ub = h * 1088;
  pre[0] = xunit_load(xn, t0, ub + tid, guard);
  pre[1] = xunit_load(xn, t0, ub + 512 + tid, guard);
  if (tid < 64) pre[2] = xunit_load(xn, t0, ub + 1024 + tid, guard);
}

__device__ __forceinline__ void xwrite_half(_Float16* __restrict__ xb, int tid,
                                            int h, const f32x4 pre[3]) {
  const int ub = h * 1088;
  xunit_write(xb, ub + tid, pre[0]);
  xunit_write(xb, ub + 512 + tid, pre[1]);
  if (tid < 64) xunit_write(xb, ub + 1024 + tid, pre[2]);
}

// ---- K-loop half: 8 k-steps (channels 4*(S0/8) .. +3) x 8 MFMA ----
// Mapping (validated R1/R4/R5): t = t0 + tlw + r + 8*c15, f = 4*g + q.
template<int S0>
__device__ __forceinline__ void khalf(const _Float16* __restrict__ wl,
                                      const _Float16* __restrict__ xb,
                                      f32x4 acc[8], int c15, int g, int tlw) {
  union Win { half8 h[2]; uint32_t d[8]; };
  #pragma unroll
  for (int s = S0; s < S0 + 8; ++s) {
    const uint32_t we = (uint32_t)(c15 * K_ + 32 * s + 8 * g);
    const half8 wf = *reinterpret_cast<const half8*>(
                         reinterpret_cast<const char*>(wl) + wswz(we));
    const int c  = s >> 1;
    const int jb = (s & 1) * 32;
    const int A0 = tlw + 8 * c15 + jb + 8 * g;   // mult of 8 -> 16B aligned
    Win win;
    win.h[0] = *reinterpret_cast<const half8*>(xb + c * XS + A0);
    win.h[1] = *reinterpret_cast<const half8*>(xb + c * XS + A0 + 8);
    #pragma unroll
    for (int r = 0; r < 8; ++r) {
      union { uint32_t d[4]; half8 h; } fr;
      const int m = r >> 1;
      if ((r & 1) == 0) {
        fr.d[0] = win.d[m];     fr.d[1] = win.d[m + 1];
        fr.d[2] = win.d[m + 2]; fr.d[3] = win.d[m + 3];
      } else {
        fr.d[0] = funnel16(win.d[m + 1], win.d[m]);
        fr.d[1] = funnel16(win.d[m + 2], win.d[m + 1]);
        fr.d[2] = funnel16(win.d[m + 3], win.d[m + 2]);
        fr.d[3] = funnel16(win.d[m + 4], win.d[m + 3]);
      }
      acc[r] = __builtin_amdgcn_mfma_f32_16x16x32_f16(wf, fr.h, acc[r], 0, 0, 0);
    }
  }
}

// ---- epilogue: register-transpose stores, alignment-exact per q ----
// (row + T) mod 16 = 4*((f + T) mod 4) = 4*q  since T is a multiple of 8.
template<bool GUARD>
__device__ __forceinline__ void epilogue(const f32x4 acc[8], f32x4 bv,
                                         float* __restrict__ outn,
                                         int T, int g) {
  #pragma unroll
  for (int q = 0; q < 4; ++q) {
    const float bias = 8.0f * bv[q];   // reference adds bias C times
    float sv[8];
    #pragma unroll
    for (int j = 0; j < 8; ++j) sv[j] = acc[j][q] + bias;
    float* row = outn + (size_t)(4 * g + q) * OW_ + T;
    if (!GUARD || T + 8 <= OW_) {
      if (q == 0) {            // 16B aligned
        *reinterpret_cast<f32x4*>(row)     = (f32x4){sv[0], sv[1], sv[2], sv[3]};
        *reinterpret_cast<f32x4*>(row + 4) = (f32x4){sv[4], sv[5], sv[6], sv[7]};
      } else if (q == 2) {     // 8B aligned
        *reinterpret_cast<f32x2*>(row)     = (f32x2){sv[0], sv[1]};
        *reinterpret_cast<f32x2*>(row + 2) = (f32x2){sv[2], sv[3]};
        *reinterpret_cast<f32x2*>(row + 4) = (f32x2){sv[4], sv[5]};
        *reinterpret_cast<f32x2*>(row + 6) = (f32x2){sv[6], sv[7]};
      } else {                 // q odd: dword, then 8B-aligned pairs
        row[0] = sv[0];
        *reinterpret_cast<f32x2*>(row + 1) = (f32x2){sv[1], sv[2]};
        *reinterpret_cast<f32x2*>(row + 3) = (f32x2){sv[3], sv[4]};
        *reinterpret_cast<f32x2*>(row + 5) = (f32x2){sv[5], sv[6]};
        row[7] = sv[7];
      }
    } else {
      #pragma unroll
      for (int j = 0; j < 8; ++j) if (T + j < OW_) row[j] = sv[j];
    }
  }
}

// One block = two 1024-t tiles (A,B) of one n, double-buffered x LDS.
// Pipeline: stage w+A -> bar -> [issue B.h0 | K(A,0-7) | write B.h0 |
// issue B.h1 | K(A,8-15) | write B.h1] -> bar -> stores(A) -> K(B) -> stores(B).
template<bool TAIL>
__device__ __forceinline__ void block_job(const float* __restrict__ x,
                                          const float* __restrict__ w,
                                          const float* __restrict__ b,
                                          float* __restrict__ out,
                                          _Float16* wl, _Float16* xb0,
                                          _Float16* xb1, int n, int tb0) {
  const int tid  = threadIdx.x;
  const int lane = tid & 63;
  const int wv   = tid >> 6;
  const int c15  = lane & 15;
  const int g    = lane >> 4;
  const int tlw  = wv << 7;

  const float* xn = x + (size_t)n * (C_ * W_);
  float* outn = out + (size_t)n * F_ * OW_;

  // ---- stage w: 8192 f32 -> f16 swizzled ----
  #pragma unroll
  for (int j = 0; j < 4; ++j) {
    int e = (tid + 512 * j) * 4;
    f32x4 v = ldx(w + e);
    u32x2 p; p[0] = pk(v[0], v[1]); p[1] = pk(v[2], v[3]);
    *reinterpret_cast<u32x2*>(reinterpret_cast<char*>(wl) + wswz((uint32_t)e)) = p;
  }

  // ---- stage x tile A (never needs guard) ----
  {
    f32x4 p0[3], p1[3];
    xload_half(xn, tb0, tid, false, 0, p0);
    xload_half(xn, tb0, tid, false, 1, p1);
    xwrite_half(xb0, tid, 0, p0);
    xwrite_half(xb0, tid, 1, p1);
  }

  const f32x4 bv = *reinterpret_cast<const f32x4*>(b + 4 * g);

  __syncthreads();

  f32x4 acc[8];
  #pragma unroll
  for (int r = 0; r < 8; ++r) acc[r] = (f32x4){0.f, 0.f, 0.f, 0.f};

  const int t0B = tb0 + TILE_T;
  f32x4 pre[3];

  // tile A compute, interleaved with tile B staging (channel-half split:
  // K-steps 0-7 read ch0-3 of A while B's ch0-3 loads are in flight)
  xload_half(xn, t0B, tid, TAIL, 0, pre);
  khalf<0>(wl, xb0, acc, c15, g, tlw);
  xwrite_half(xb1, tid, 0, pre);
  xload_half(xn, t0B, tid, TAIL, 1, pre);
  khalf<8>(wl, xb0, acc, c15, g, tlw);
  xwrite_half(xb1, tid, 1, pre);

  __syncthreads();   // no vm ops outstanding here -> cheap drain

  // tile A stores (drain under tile B compute)
  epilogue<false>(acc, bv, outn, tb0 + tlw + 8 * c15, g);

  #pragma unroll
  for (int r = 0; r < 8; ++r) acc[r] = (f32x4){0.f, 0.f, 0.f, 0.f};

  khalf<0>(wl, xb1, acc, c15, g, tlw);
  khalf<8>(wl, xb1, acc, c15, g, tlw);

  epilogue<TAIL>(acc, bv, outn, t0B + tlw + 8 * c15, g);
}

__global__ __launch_bounds__(512, 6)
void corr1d(const float* __restrict__ x, const float* __restrict__ w,
            const float* __restrict__ b, float* __restrict__ out) {
  __shared__ __align__(16) _Float16 wl[F_ * K_];   // 16 KB
  __shared__ __align__(16) _Float16 xb[2][XBUF];   // 2 x 18 KB

  const int n  = blockIdx.x >> 5;      // 32 n
  const int bt = blockIdx.x & 31;      // 32 t-blocks of 2048
  const int tb0 = bt << 11;

  if (bt < 31) block_job<false>(x, w, b, out, wl, xb[0], xb[1], n, tb0);
  else         block_job<true >(x, w, b, out, wl, xb[0], xb[1], n, tb0);
}

extern "C" void kernel_launch(void* const* d_in, const int* in_sizes, int n_in,
                              void* d_out, int out_size, void* d_ws, size_t ws_size,
                              hipStream_t stream) {
  (void)in_sizes; (void)n_in; (void)out_size; (void)d_ws; (void)ws_size;
  const float* x = (const float*)d_in[0];
  const float* w = (const float*)d_in[1];
  const float* b = (const float*)d_in[2];
  float* out = (float*)d_out;
  corr1d<<<dim3(32 * 32), dim3(512), 0, stream>>>(x, w, b, out);
}

// Round 9
// 53.404 us; speedup vs baseline: 1.3712x; 1.3712x over previous
//
#include <hip/hip_runtime.h>
#include <stdint.h>

typedef _Float16 half8 __attribute__((ext_vector_type(8)));
typedef __fp16 fp16x2 __attribute__((ext_vector_type(2)));
typedef float f32x4 __attribute__((ext_vector_type(4)));
typedef float f32x2 __attribute__((ext_vector_type(2)));
typedef uint32_t u32x2 __attribute__((ext_vector_type(2)));

#define N_ 32
#define C_ 8
#define W_ 65536
#define F_ 16
#define OW_ 65473
#define K_ 512
#define TILE_T 512
#define XS 608               // halfs per channel row in LDS (512 + 64 halo + pad)

// funnel16(hi, lo) = (hi:lo) >> 16  -> v_alignbit_b32
__device__ __forceinline__ uint32_t funnel16(uint32_t hi, uint32_t lo) {
  return (uint32_t)((((uint64_t)hi << 32) | (uint64_t)lo) >> 16);
}

// pack two f32 -> one dword of 2x f16 (v_cvt_pkrtz_f16_f32)
__device__ __forceinline__ uint32_t pk(float a, float b) {
  union { fp16x2 h; uint32_t u; } cv;
  cv.h = __builtin_amdgcn_cvt_pkrtz(a, b);
  return cv.u;
}

// w LDS swizzle (half-index, mult of 4): XOR chunk idx with bits 6-8 (=c15&7)
__device__ __forceinline__ uint32_t wswz(uint32_t e) {
  uint32_t ch = e >> 3;
  ch ^= (ch >> 6) & 7u;
  return (ch << 4) | ((e & 7u) << 1);
}

__device__ __forceinline__ f32x4 ldx(const float* p) {
  return *reinterpret_cast<const f32x4*>(p);
}

// One block = one 512-t tile of one n. Small blocks -> 6 resident/CU with
// independent barriers; cross-block staggering supplies the stage/compute/
// store overlap (R7's intra-block pipeline spilled; this doesn't).
// Mapping (validated R1/R4/R5): t = t0 + tlw + r + 8*c15, f = 4*g + q.
template<bool TAIL>
__device__ __forceinline__ void block_job(const float* __restrict__ x,
                                          const float* __restrict__ w,
                                          const float* __restrict__ b,
                                          float* __restrict__ out,
                                          _Float16* wl, _Float16* xb,
                                          int n, int t0) {
  const int tid  = threadIdx.x;
  const int lane = tid & 63;
  const int wv   = tid >> 6;           // 0..3
  const int c15  = lane & 15;
  const int g    = lane >> 4;

  const float* xn = x + (size_t)n * (C_ * W_);

  // ---- stage w: 8192 f32 -> f16 swizzled (8 f32x4 per thread) ----
  #pragma unroll
  for (int j = 0; j < 8; ++j) {
    int e = (tid + 256 * j) * 4;
    f32x4 v = ldx(w + e);
    u32x2 p; p[0] = pk(v[0], v[1]); p[1] = pk(v[2], v[3]);
    *reinterpret_cast<u32x2*>(reinterpret_cast<char*>(wl) + wswz((uint32_t)e)) = p;
  }

  // ---- stage x: 1152 f32x4 units = 8 ch x 144 (576 halfs each) ----
  #pragma unroll
  for (int j = 0; j < 5; ++j) {
    int u = tid + 256 * j;
    if (j == 4 && u >= 1152) break;     // 5th pass: only 128 threads
    int ch = u / 144;
    int pos = (u - ch * 144) * 4;       // 0..572
    int gi = t0 + pos;
    f32x4 v;
    if (TAIL) v = (gi < W_) ? ldx(xn + (size_t)ch * W_ + gi) : (f32x4){0.f,0.f,0.f,0.f};
    else      v = ldx(xn + (size_t)ch * W_ + gi);
    u32x2 p; p[0] = pk(v[0], v[1]); p[1] = pk(v[2], v[3]);
    *reinterpret_cast<u32x2*>(reinterpret_cast<char*>(xb) + (size_t)(ch * XS + pos) * 2u) = p;
  }

  const f32x4 bv = *reinterpret_cast<const f32x4*>(b + 4 * g);

  __syncthreads();   // the only barrier

  const int tlw = wv << 7;             // wave's 128-t slice (0..384)

  f32x4 acc[8];
  #pragma unroll
  for (int r = 0; r < 8; ++r) acc[r] = (f32x4){0.f, 0.f, 0.f, 0.f};

  union Win { half8 h[2]; uint32_t d[8]; };

  #pragma unroll
  for (int s = 0; s < 16; ++s) {
    const uint32_t we = (uint32_t)(c15 * K_ + 32 * s + 8 * g);
    const half8 wf = *reinterpret_cast<const half8*>(
                         reinterpret_cast<const char*>(wl) + wswz(we));
    const int c  = s >> 1;
    const int jb = (s & 1) * 32;
    const int A0 = tlw + 8 * c15 + jb + 8 * g;   // mult of 8 -> 16B aligned
    Win win;
    win.h[0] = *reinterpret_cast<const half8*>(xb + c * XS + A0);
    win.h[1] = *reinterpret_cast<const half8*>(xb + c * XS + A0 + 8);
    #pragma unroll
    for (int r = 0; r < 8; ++r) {
      union { uint32_t d[4]; half8 h; } fr;
      const int m = r >> 1;
      if ((r & 1) == 0) {
        fr.d[0] = win.d[m];     fr.d[1] = win.d[m + 1];
        fr.d[2] = win.d[m + 2]; fr.d[3] = win.d[m + 3];
      } else {
        fr.d[0] = funnel16(win.d[m + 1], win.d[m]);
        fr.d[1] = funnel16(win.d[m + 2], win.d[m + 1]);
        fr.d[2] = funnel16(win.d[m + 3], win.d[m + 2]);
        fr.d[3] = funnel16(win.d[m + 4], win.d[m + 3]);
      }
      acc[r] = __builtin_amdgcn_mfma_f32_16x16x32_f16(wf, fr.h, acc[r], 0, 0, 0);
    }
  }

  // ---- epilogue: register-transpose stores, alignment-exact per q ----
  // (row + T) mod 16 = 4*((f + T) mod 4) = 4*q  since T is a multiple of 8.
  const int T = t0 + tlw + 8 * c15;
  float* outn = out + (size_t)n * F_ * OW_;
  #pragma unroll
  for (int q = 0; q < 4; ++q) {
    const float bias = 8.0f * bv[q];   // reference adds bias C times
    float sv[8];
    #pragma unroll
    for (int j = 0; j < 8; ++j) sv[j] = acc[j][q] + bias;
    float* row = outn + (size_t)(4 * g + q) * OW_ + T;
    if (!TAIL || T + 8 <= OW_) {
      if (q == 0) {            // 16B aligned
        *reinterpret_cast<f32x4*>(row)     = (f32x4){sv[0], sv[1], sv[2], sv[3]};
        *reinterpret_cast<f32x4*>(row + 4) = (f32x4){sv[4], sv[5], sv[6], sv[7]};
      } else if (q == 2) {     // 8B aligned
        *reinterpret_cast<f32x2*>(row)     = (f32x2){sv[0], sv[1]};
        *reinterpret_cast<f32x2*>(row + 2) = (f32x2){sv[2], sv[3]};
        *reinterpret_cast<f32x2*>(row + 4) = (f32x2){sv[4], sv[5]};
        *reinterpret_cast<f32x2*>(row + 6) = (f32x2){sv[6], sv[7]};
      } else {                 // q odd: dword, then 8B-aligned pairs
        row[0] = sv[0];
        *reinterpret_cast<f32x2*>(row + 1) = (f32x2){sv[1], sv[2]};
        *reinterpret_cast<f32x2*>(row + 3) = (f32x2){sv[3], sv[4]};
        *reinterpret_cast<f32x2*>(row + 5) = (f32x2){sv[5], sv[6]};
        row[7] = sv[7];
      }
    } else {
      #pragma unroll
      for (int j = 0; j < 8; ++j) if (T + j < OW_) row[j] = sv[j];
    }
  }
}

__global__ __launch_bounds__(256, 6)
void corr1d(const float* __restrict__ x, const float* __restrict__ w,
            const float* __restrict__ b, float* __restrict__ out) {
  __shared__ __align__(16) _Float16 wl[F_ * K_];   // 16 KB
  __shared__ __align__(16) _Float16 xb[C_ * XS];   // 9.5 KB

  const int n  = blockIdx.x >> 7;      // 32 n
  const int tt = blockIdx.x & 127;     // 128 tiles of 512 t
  const int t0 = tt * TILE_T;

  if (tt < 127) block_job<false>(x, w, b, out, wl, xb, n, t0);
  else          block_job<true >(x, w, b, out, wl, xb, n, t0);
}

extern "C" void kernel_launch(void* const* d_in, const int* in_sizes, int n_in,
                              void* d_out, int out_size, void* d_ws, size_t ws_size,
                              hipStream_t stream) {
  (void)in_sizes; (void)n_in; (void)out_size; (void)d_ws; (void)ws_size;
  const float* x = (const float*)d_in[0];
  const float* w = (const float*)d_in[1];
  const float* b = (const float*)d_in[2];
  float* out = (float*)d_out;
  corr1d<<<dim3(32 * 128), dim3(256), 0, stream>>>(x, w, b, out);
}

// Round 10
// 50.677 us; speedup vs baseline: 1.4450x; 1.0538x over previous
//
#include <hip/hip_runtime.h>
#include <stdint.h>

typedef _Float16 half8 __attribute__((ext_vector_type(8)));
typedef __fp16 fp16x2 __attribute__((ext_vector_type(2)));
typedef float f32x4 __attribute__((ext_vector_type(4)));
typedef float f32x2 __attribute__((ext_vector_type(2)));
typedef uint32_t u32x2 __attribute__((ext_vector_type(2)));

#define N_ 32
#define C_ 8
#define W_ 65536
#define F_ 16
#define OW_ 65473
#define K_ 512
#define TILE_T 1024
#define XS 1152              // halfs per channel row in x LDS (1024 + 128 halo)
#define SCP 140              // scratch row stride in floats (140*4=560B, 16B-mult)
#define SCW 4480             // scratch bytes per wave = 8 rows * 560

// funnel16(hi, lo) = (hi:lo) >> 16  -> v_alignbit_b32
__device__ __forceinline__ uint32_t funnel16(uint32_t hi, uint32_t lo) {
  return (uint32_t)((((uint64_t)hi << 32) | (uint64_t)lo) >> 16);
}

// pack two f32 -> one dword of 2x f16 (v_cvt_pkrtz_f16_f32)
__device__ __forceinline__ uint32_t pk(float a, float b) {
  union { fp16x2 h; uint32_t u; } cv;
  cv.h = __builtin_amdgcn_cvt_pkrtz(a, b);
  return cv.u;
}

// w LDS swizzle (half-index, mult of 4): XOR chunk idx with bits 6-8 (=c15&7)
__device__ __forceinline__ uint32_t wswz(uint32_t e) {
  uint32_t ch = e >> 3;
  ch ^= (ch >> 6) & 7u;
  return (ch << 4) | ((e & 7u) << 1);
}

__device__ __forceinline__ f32x4 ldx(const float* p) {
  return *reinterpret_cast<const f32x4*>(p);
}

// One block = one 1024-t tile of one n.
// stage w+x -> bar -> K-loop (16 steps x 8 MFMA, sliding-window frags) ->
// bar -> per-wave LDS transpose (scratch overlays dead wl/xb) ->
// line-exact coalesced stores (every 8-lane f32x2 group = one 64B line).
// Mapping (validated R1-R8): t = t0 + tlw + r + 8*c15, f = 4*g + q.
template<bool TAIL>
__device__ __forceinline__ void block_job(const float* __restrict__ x,
                                          const float* __restrict__ w,
                                          const float* __restrict__ b,
                                          float* __restrict__ out,
                                          char* smem, int n, int t0) {
  _Float16* wl = reinterpret_cast<_Float16*>(smem);            // 16 KB
  _Float16* xb = reinterpret_cast<_Float16*>(smem + 16384);    // 18 KB

  const int tid  = threadIdx.x;
  const int lane = tid & 63;
  const int wv   = tid >> 6;           // 0..7
  const int c15  = lane & 15;
  const int g    = lane >> 4;

  const float* xn = x + (size_t)n * (C_ * W_);

  // ---- stage w: 8192 f32 -> f16 swizzled (4 f32x4 per thread) ----
  #pragma unroll
  for (int j = 0; j < 4; ++j) {
    int e = (tid + 512 * j) * 4;
    f32x4 v = ldx(w + e);
    u32x2 p; p[0] = pk(v[0], v[1]); p[1] = pk(v[2], v[3]);
    *reinterpret_cast<u32x2*>(reinterpret_cast<char*>(wl) + wswz((uint32_t)e)) = p;
  }

  // ---- stage x: 2176 f32x4 units = 8 ch x 272 ----
  #pragma unroll
  for (int j = 0; j < 5; ++j) {
    int u = tid + 512 * j;
    if (j == 4 && u >= 2176) break;     // 5th pass: only 128 threads
    int ch = u / 272;
    int pos = (u - ch * 272) * 4;       // 0..1084
    int gi = t0 + pos;
    f32x4 v;
    if (TAIL) v = (gi < W_) ? ldx(xn + (size_t)ch * W_ + gi) : (f32x4){0.f,0.f,0.f,0.f};
    else      v = ldx(xn + (size_t)ch * W_ + gi);
    u32x2 p; p[0] = pk(v[0], v[1]); p[1] = pk(v[2], v[3]);
    *reinterpret_cast<u32x2*>(reinterpret_cast<char*>(xb) + (size_t)(ch * XS + pos) * 2u) = p;
  }

  const f32x4 bv = *reinterpret_cast<const f32x4*>(b + 4 * g);

  __syncthreads();

  const int tlw = wv << 7;             // wave's 128-t slice

  f32x4 acc[8];
  #pragma unroll
  for (int r = 0; r < 8; ++r) acc[r] = (f32x4){0.f, 0.f, 0.f, 0.f};

  union Win { half8 h[2]; uint32_t d[8]; };

  #pragma unroll
  for (int s = 0; s < 16; ++s) {
    const uint32_t we = (uint32_t)(c15 * K_ + 32 * s + 8 * g);
    const half8 wf = *reinterpret_cast<const half8*>(
                         reinterpret_cast<const char*>(wl) + wswz(we));
    const int c  = s >> 1;
    const int jb = (s & 1) * 32;
    const int A0 = tlw + 8 * c15 + jb + 8 * g;   // mult of 8 -> 16B aligned
    Win win;
    win.h[0] = *reinterpret_cast<const half8*>(xb + c * XS + A0);
    win.h[1] = *reinterpret_cast<const half8*>(xb + c * XS + A0 + 8);
    #pragma unroll
    for (int r = 0; r < 8; ++r) {
      union { uint32_t d[4]; half8 h; } fr;
      const int m = r >> 1;
      if ((r & 1) == 0) {
        fr.d[0] = win.d[m];     fr.d[1] = win.d[m + 1];
        fr.d[2] = win.d[m + 2]; fr.d[3] = win.d[m + 3];
      } else {
        fr.d[0] = funnel16(win.d[m + 1], win.d[m]);
        fr.d[1] = funnel16(win.d[m + 2], win.d[m + 1]);
        fr.d[2] = funnel16(win.d[m + 3], win.d[m + 2]);
        fr.d[3] = funnel16(win.d[m + 4], win.d[m + 3]);
      }
      acc[r] = __builtin_amdgcn_mfma_f32_16x16x32_f16(wf, fr.h, acc[r], 0, 0, 0);
    }
  }

  __syncthreads();   // all waves done reading wl/xb -> reuse as scratch

  // ---- epilogue: per-wave LDS transpose -> line-exact stores ----
  float* sc = reinterpret_cast<float*>(smem + (size_t)wv * SCW);
  float* outn = out + (size_t)n * F_ * OW_;
  const int Tw  = t0 + tlw;            // multiple of 128
  const int flr = lane >> 3;           // read role: f-row 0..7
  const int k   = lane & 7;            // read role: 8 lanes per row

  #pragma unroll
  for (int cb = 0; cb < 2; ++cb) {
    const int qb = 2 * cb;
    // write phase: lane (c15,g) deposits q=qb..qb+1 (rows fl=2g+dq)
    #pragma unroll
    for (int dq = 0; dq < 2; ++dq) {
      const int q  = qb + dq;
      const int fl = 2 * g + dq;
      const float bias = 8.0f * bv[q];   // reference adds bias C times
      f32x4 lo = { acc[0][q] + bias, acc[1][q] + bias,
                   acc[2][q] + bias, acc[3][q] + bias };
      f32x4 hi = { acc[4][q] + bias, acc[5][q] + bias,
                   acc[6][q] + bias, acc[7][q] + bias };
      *reinterpret_cast<f32x4*>(sc + fl * SCP + 8 * c15)     = lo;
      *reinterpret_cast<f32x4*>(sc + fl * SCP + 8 * c15 + 4) = hi;
    }
    // read+store phase: row f, 64B groups start at tf so each 8-lane
    // f32x2 group covers exactly one 64B line (OW % 16 == 1).
    const int f  = 4 * (flr >> 1) + qb + (flr & 1);
    const int tf = (16 - f) & 15;
    float* row = outn + (size_t)f * OW_ + Tw;
    #pragma unroll
    for (int j = 0; j < 7; ++j) {
      const int t = tf + 2 * k + 16 * j;
      f32x2 v = { sc[flr * SCP + t], sc[flr * SCP + t + 1] };
      if (!TAIL || Tw + t + 2 <= OW_) {
        *reinterpret_cast<f32x2*>(row + t) = v;
      } else {
        if (Tw + t     < OW_) row[t]     = v[0];
        if (Tw + t + 1 < OW_) row[t + 1] = v[1];
      }
    }
    #pragma unroll
    for (int e2 = 0; e2 < 2; ++e2) {
      const int e = k + 8 * e2;
      const int t = (e < tf) ? e : 112 + e;
      if (!TAIL || Tw + t < OW_) row[t] = sc[flr * SCP + t];
    }
  }
}

__global__ __launch_bounds__(512, 6)
void corr1d(const float* __restrict__ x, const float* __restrict__ w,
            const float* __restrict__ b, float* __restrict__ out) {
  __shared__ __align__(16) char smem[35840];   // wl(16K)+xb(18K) / scratch(35K)

  const int n  = blockIdx.x >> 6;      // 32 n
  const int tt = blockIdx.x & 63;      // 64 tiles of 1024 t
  const int t0 = tt * TILE_T;

  if (tt < 63) block_job<false>(x, w, b, out, smem, n, t0);
  else         block_job<true >(x, w, b, out, smem, n, t0);
}

extern "C" void kernel_launch(void* const* d_in, const int* in_sizes, int n_in,
                              void* d_out, int out_size, void* d_ws, size_t ws_size,
                              hipStream_t stream) {
  (void)in_sizes; (void)n_in; (void)out_size; (void)d_ws; (void)ws_size;
  const float* x = (const float*)d_in[0];
  const float* w = (const float*)d_in[1];
  const float* b = (const float*)d_in[2];
  float* out = (float*)d_out;
  corr1d<<<dim3(32 * 64), dim3(512), 0, stream>>>(x, w, b, out);
}